// Round 18
// baseline (2263.277 us; speedup 1.0000x reference)
//
#include <hip/hip_runtime.h>
#include <cstdint>
#include <math.h>

// GREEN since r6. Best r15/r17 = 489/495us (476 per-dispatch, identical).
// r17 plateau analysis: latency-bound mixed (VALU 57%, DS ~58%), waves/SIMD
// pinned at 2 by grid (2048 blocks = 8/CU) AND LDS (20480B x 8 = 160KiB
// exactly). Structure change required, not tweaks.
// THIS ROUND: CPB=1 (4096 waves -> 3/SIMD at VGPR<=170) + Un moved OFF the
// DS pipe to the idle VMEM/L1 pipe: pre-kernel transposes Un into d_ws
// (UnT[j][k], 16KB = L1-resident, shared by all blocks on a CU); dot reads it
// as per-lane global dwordx4 with depth-4 rotating VOLATILE prefetch
// (volatile prevents LICM hoisting of loop-invariant loads = the r14 AGPR
// trap, while allowing ~12 outstanding). Unlike r13/r14/r16 (relocated work
// onto the BUSY VALU -> lost), this targets an idle pipe. FMA values and
// k-order bit-identical (exact copy, no reduction-order change).
// EMPIRICAL RULES: only __launch_bounds__(64,1) gives the full reg budget
// ((64,N>1) caps at 512/N -> r8 disaster); OccupancyPercent counter is a
// gfx94x fallback (untrustworthy); decisions rounding-robust (6 variants
// bit-identical). PRNG = partitionable threefry (key_t = tf((0,42),(0,t));
// bits = o0^o1 of tf(key_t,(0,2s+cat))); f32 in/out; out = [4096*144][4096].

#define NSAMP 4096
#define NSTEP 144
#define HID 64

typedef float v16f __attribute__((ext_vector_type(16)));
typedef float v4f  __attribute__((ext_vector_type(4)));

// ---- JAX threefry2x32 (20 rounds, key-inject every 4) ----
__device__ __forceinline__ void threefry2x32(uint32_t k0, uint32_t k1,
                                             uint32_t x0, uint32_t x1,
                                             uint32_t& o0, uint32_t& o1) {
  const uint32_t ks0 = k0, ks1 = k1, ks2 = k0 ^ k1 ^ 0x1BD11BDAu;
  x0 += ks0; x1 += ks1;
#define TF_ROUND(d) { x0 += x1; x1 = (x1 << (d)) | (x1 >> (32 - (d))); x1 ^= x0; }
  TF_ROUND(13) TF_ROUND(15) TF_ROUND(26) TF_ROUND(6)
  x0 += ks1; x1 += ks2 + 1u;
  TF_ROUND(17) TF_ROUND(29) TF_ROUND(16) TF_ROUND(24)
  x0 += ks2; x1 += ks0 + 2u;
  TF_ROUND(13) TF_ROUND(15) TF_ROUND(26) TF_ROUND(6)
  x0 += ks0; x1 += ks1 + 3u;
  TF_ROUND(17) TF_ROUND(29) TF_ROUND(16) TF_ROUND(24)
  x0 += ks1; x1 += ks2 + 4u;
  TF_ROUND(13) TF_ROUND(15) TF_ROUND(26) TF_ROUND(6)
  x0 += ks2; x1 += ks0 + 5u;
#undef TF_ROUND
  o0 = x0; o1 = x1;
}

// fast branch-free f32 transcendentals (raw v_exp_f32 / v_log_f32 / v_rcp_f32)
__device__ __forceinline__ float fsig(float x) {        // 1/(1+e^-x), stable
  return __builtin_amdgcn_rcpf(1.0f + __expf(-x));
}
__device__ __forceinline__ float ftanh(float x) {       // 1 - 2/(e^2x+1)
  const float e = __expf(2.0f * x);
  return 1.0f - 2.0f * __builtin_amdgcn_rcpf(e + 1.0f);
}

// pre-kernel: UnT[j*64 + k] = Un[k][j]  (exact bit-copy, 16KB into d_ws)
__global__ void transpose_un_kernel(const float* __restrict__ U,
                                    float* __restrict__ unT) {
  const int j = threadIdx.x;
#pragma unroll 1
  for (int k = 0; k < HID; ++k)
    unT[j * HID + k] = U[k * 192 + 128 + j];
}

__global__ __launch_bounds__(64, 1) void vmc_kernel(
    const float* __restrict__ W, const float* __restrict__ U,
    const float* __restrict__ B, const float* __restrict__ Wd,
    const float* __restrict__ Bd, const float* __restrict__ unT,
    float* __restrict__ out) {
  const int j = threadIdx.x;           // hidden unit owned by this lane
  const int s = blockIdx.x;            // one chain per (single-wave) block

  __shared__ __align__(16) float hsh[HID];         // h[unit]
  __shared__ uint2 kkeys[NSTEP];
  __shared__ __align__(8) float gsh[2 * NSTEP];    // gumbels [2t + cat]

  // --- per-step keys: key_t = threefry((0,42),(0,t)) ---
#pragma unroll 1
  for (int t = j; t < NSTEP; t += HID) {
    uint32_t o0, o1;
    threefry2x32(0u, 42u, 0u, (uint32_t)t, o0, o1);
    kkeys[t].x = o0; kkeys[t].y = o1;
  }
  hsh[j] = 0.0f;
  __syncthreads();

  // --- gumbels: EXACT f64 path (one-time): bits = o0^o1 of tf(key_t,(0,2s+c))
#pragma unroll 1
  for (int id = j; id < 2 * NSTEP; id += HID) {
    const uint2 kt = kkeys[id >> 1];
    const uint32_t i = 2u * (uint32_t)s + (uint32_t)(id & 1);
    uint32_t o0, o1;
    threefry2x32(kt.x, kt.y, 0u, i, o0, o1);
    const uint32_t bits = o0 ^ o1;
    union { uint32_t u; float f; } cv; cv.u = (bits >> 9) | 0x3F800000u;
    float uf = cv.f - 1.0f;
    uf = fmaxf(uf, 1.17549435e-38f);
    const float inner = (float)log((double)uf);
    gsh[id] = -(float)log((double)(-inner));
  }
  __syncthreads();

  // --- Uz, Ur columns for unit j: register-resident (128 floats, proven) ---
  v16f uz0, uz1, uz2, uz3, ur0, ur1, ur2, ur3;
#define LOADB(v, r, off) \
  { _Pragma("unroll") for (int e = 0; e < 16; ++e) v[e] = U[((r)*16 + e)*192 + (off) + j]; }
  LOADB(uz0, 0, 0)   LOADB(uz1, 1, 0)   LOADB(uz2, 2, 0)   LOADB(uz3, 3, 0)
  LOADB(ur0, 0, 64)  LOADB(ur1, 1, 64)  LOADB(ur2, 2, 64)  LOADB(ur3, 3, 64)
#undef LOADB

  // Un column j via L1-resident transposed table; volatile = no LICM hoist
  const volatile v4f* unp = (const volatile v4f*)(unT + j * HID);

  const float b1z = B[192 + j], b1r = B[256 + j], b1n = B[320 + j];
  const float b0z = B[j],       b0r = B[64 + j],  b0n = B[128 + j];
  const float xW0z = W[j]       + b0z, xW1z = W[192 + j] + b0z;
  const float xW0r = W[64 + j]  + b0r, xW1r = W[256 + j] + b0r;
  const float xW0n = W[128 + j] + b0n, xW1n = W[320 + j] + b0n;
  const float wdd = Wd[2*j + 1] - Wd[2*j];   // dense difference column
  const float bdd = Bd[1] - Bd[0];

  float ha = 0.0f, logPa = 0.0f;
  float axz = b0z, axr = b0r, axn = b0n;  // t=0: x=0 -> xm = b[0]
  float hza = 0.f, hra = 0.f, hna = 0.f;  // loop-carried dot; h_{-1}=0

  for (int t = 0; t < NSTEP; ++t) {
    // ---- gates from the PREVIOUS iteration's dot (software pipeline) ----
    {
      const float az = axz + (hza + b1z), ar = axr + (hra + b1r);
      const float zz = fsig(az), rr = fsig(ar);
      const float hh = ftanh(axn + rr * (hna + b1n));
      ha = zz * ha + (1.0f - zz) * hh;
    }
    hsh[j] = ha;   // single wave: LDS ops in program order

    // ---- dense: difference-reduction + single-exp sigmoid pair (proven) ----
    float da = ha * wdd;
#pragma unroll
    for (int m = 1; m < 64; m <<= 1) da += __shfl_xor(da, m, 64);
    int sma;
    {
      const float d = da + bdd;
      const float e = __expf(-d);
      const float p1 = __builtin_amdgcn_rcpf(1.0f + e);
      const float lp1 = __logf(1e-10f + p1);
      const float lp0 = __logf(1e-10f + e * p1);
      const float2 g = *(const float2*)&gsh[2*t];
      sma = (lp1 + g.y) > (lp0 + g.x);
      logPa += sma ? lp1 : lp0;
      axz = sma ? xW1z : xW0z;
      axr = sma ? xW1r : xW0r;
      axn = sma ? xW1n : xW0n;
    }
    if (j == 0) out[s * NSTEP + t] = sma ? 1.0f : 0.0f;

    // ---- dot for NEXT step: hm = h_t @ U, k-ascending FMA from 0.
    // h via uniform LDS b128 broadcast; Un via depth-4 volatile global
    // dwordx4 prefetch (L1-hit). Values + order bit-identical to r17. ----
    hza = 0.f; hra = 0.f; hna = 0.f;
    v4f n0 = unp[0], n1 = unp[1], n2 = unp[2], n3 = unp[3];
#define USE(cc, uzv, urv, nv) \
    { const float4 hv = *(const float4*)&hsh[4*(cc)]; \
      const int e_ = ((cc) & 3) * 4; \
      hza = __builtin_fmaf(hv.x, uzv[e_+0], hza); \
      hra = __builtin_fmaf(hv.x, urv[e_+0], hra); \
      hna = __builtin_fmaf(hv.x, nv.x,      hna); \
      hza = __builtin_fmaf(hv.y, uzv[e_+1], hza); \
      hra = __builtin_fmaf(hv.y, urv[e_+1], hra); \
      hna = __builtin_fmaf(hv.y, nv.y,      hna); \
      hza = __builtin_fmaf(hv.z, uzv[e_+2], hza); \
      hra = __builtin_fmaf(hv.z, urv[e_+2], hra); \
      hna = __builtin_fmaf(hv.z, nv.z,      hna); \
      hza = __builtin_fmaf(hv.w, uzv[e_+3], hza); \
      hra = __builtin_fmaf(hv.w, urv[e_+3], hra); \
      hna = __builtin_fmaf(hv.w, nv.w,      hna); }
    USE(0,  uz0, ur0, n0)  n0 = unp[4];
    USE(1,  uz0, ur0, n1)  n1 = unp[5];
    USE(2,  uz0, ur0, n2)  n2 = unp[6];
    USE(3,  uz0, ur0, n3)  n3 = unp[7];
    USE(4,  uz1, ur1, n0)  n0 = unp[8];
    USE(5,  uz1, ur1, n1)  n1 = unp[9];
    USE(6,  uz1, ur1, n2)  n2 = unp[10];
    USE(7,  uz1, ur1, n3)  n3 = unp[11];
    USE(8,  uz2, ur2, n0)  n0 = unp[12];
    USE(9,  uz2, ur2, n1)  n1 = unp[13];
    USE(10, uz2, ur2, n2)  n2 = unp[14];
    USE(11, uz2, ur2, n3)  n3 = unp[15];
    USE(12, uz3, ur3, n0)
    USE(13, uz3, ur3, n1)
    USE(14, uz3, ur3, n2)
    USE(15, uz3, ur3, n3)
#undef USE
  }

  if (j == 0) out[NSAMP * NSTEP + s] = logPa;
}

extern "C" void kernel_launch(void* const* d_in, const int* in_sizes, int n_in,
                              void* d_out, int out_size, void* d_ws, size_t ws_size,
                              hipStream_t stream) {
  // inputs (setup_inputs order): nsamples(1), W(2x192), U(64x192), b(2x192),
  // Wd(64x2), bd(2) — float32
  const float* W  = (const float*)d_in[1];
  const float* U  = (const float*)d_in[2];
  const float* B  = (const float*)d_in[3];
  const float* Wd = (const float*)d_in[4];
  const float* Bd = (const float*)d_in[5];
  float* unT = (float*)d_ws;                     // 16 KB transposed Un table
  transpose_un_kernel<<<dim3(1), dim3(HID), 0, stream>>>(U, unT);
  vmc_kernel<<<dim3(NSAMP), dim3(HID), 0, stream>>>(W, U, B, Wd, Bd, unT,
                                                    (float*)d_out);
}